// Round 8
// baseline (339.869 us; speedup 1.0000x reference)
//
#include <hip/hip_runtime.h>

typedef __attribute__((ext_vector_type(4))) float f32x4;
typedef __attribute__((ext_vector_type(8))) short s16x8;

#define NG     8000
#define NRPT   8000
#define NSKIN  128
#define MT     128
#define NT     64
#define KK     32
#define KCH    800
#define NKC    10
#define NTILES 25          // KCH/KK exact
#define NRB    125         // NRPT/NT exact
#define TPB    256
#define WS_TILE_B 16384    // per K-tile: Ar 8KB + Ai 8KB, pre-swizzled bf16
#define WS_NEED   ((size_t)NKC*NTILES*WS_TILE_B)   // 4,096,000 B

// LDS byte offsets inside smem
#define S_AR 0
#define S_AI 8192
#define S_BC 16384
#define S_BS 20480
#define S_SZ 24576

__device__ __forceinline__ float sin_rev(float u){ float r; asm("v_sin_f32 %0, %1" : "=v"(r) : "v"(u)); return r; }
__device__ __forceinline__ float cos_rev(float u){ float r; asm("v_cos_f32 %0, %1" : "=v"(r) : "v"(u)); return r; }
__device__ __forceinline__ unsigned int cvt_pk(float lo, float hi){
    unsigned int r; asm("v_cvt_pk_bf16_f32 %0, %1, %2" : "=v"(r) : "v"(lo), "v"(hi)); return r;
}
__device__ __forceinline__ s16x8 bneg(s16x8 v){
    int4 u = *(int4*)&v;
    u.x ^= 0x80008000; u.y ^= 0x80008000; u.z ^= 0x80008000; u.w ^= 0x80008000;
    return *(s16x8*)&u;
}
// swizzled byte offset of 16B granule (row,kg) in a [rows][32]-ushort tile (64B rows).
// kg' = kg ^ ((row>>1)&3): both b128 stage-writes and b128 frag reads land
// 8 lanes per 16B bank-group -> conflict-free. Invariant under row+16 (+1024B).
__device__ __forceinline__ int swz(int row, int kg){
    return row*64 + ((kg ^ ((row>>1)&3))<<4);
}
__device__ __forceinline__ void glds16(const void* g, void* l){
    __builtin_amdgcn_global_load_lds((const __attribute__((address_space(1))) void*)g,
                                     (__attribute__((address_space(3))) void*)l, 16, 0, 0);
}

// ---- pre-pass: cg fp32 -> bf16 in pre-swizzled K-tile order ----
// ws granule gid (16B): gid = ((kc*25+t)*2 + plane)*512 + row*4 + slot
// content = bf16 of cg[row][kc*800 + t*32 + kg*8 .. +8], kg = slot ^ ((row>>1)&3)
__global__ __launch_bounds__(256) void bloch_prepass(
    const float* __restrict__ cgr, const float* __restrict__ cgi,
    char* __restrict__ ws)
{
    int gid = blockIdx.x*256 + threadIdx.x;
    if (gid >= NKC*NTILES*2*512) return;
    int slot  = gid & 3;
    int row   = (gid >> 2) & 127;
    int pt    = gid >> 9;
    int plane = pt & 1;
    int tileIdx = pt >> 1;          // kc*25 + t
    int t  = tileIdx % NTILES;
    int kc = tileIdx / NTILES;
    int kg = slot ^ ((row >> 1) & 3);
    int k  = kc*KCH + t*KK + kg*8;
    const float* src = plane ? cgi : cgr;
    const float4 v0 = *(const float4*)&src[(size_t)row*NG + k];
    const float4 v1 = *(const float4*)&src[(size_t)row*NG + k + 4];
    uint4 p;
    p.x = cvt_pk(v0.x, v0.y); p.y = cvt_pk(v0.z, v0.w);
    p.z = cvt_pk(v1.x, v1.y); p.w = cvt_pk(v1.z, v1.w);
    *(uint4*)(ws + (size_t)gid*16) = p;
}

template<bool PRE>
__global__ __launch_bounds__(TPB, 6) void bloch7(
    const float* __restrict__ Amat, const float* __restrict__ kgrid,
    const float* __restrict__ cgr,  const float* __restrict__ cgi,
    const float* __restrict__ rpts, const char* __restrict__ ws,
    float* __restrict__ out, int out_size)
{
    __shared__ __align__(16) char smem[S_SZ];   // A(16K)|Bc(4K)|Bs(4K); ekr overlay after loop
    __shared__ float fracS[NT][4];
    __shared__ float invAS[9];
    __shared__ float scaleS;

    const int tid = threadIdx.x;
    const int bid = blockIdx.x;
    // kc-partners of an output tile are 128 apart in bid -> same bid%8 -> same XCD
    const int kc  = bid >> 7;           // 0..9
    const int rb  = bid & 127;          // 0..127
    if (rb >= NRB) return;
    const int r_base  = rb * NT;
    const int k_begin = kc * KCH;

    if (tid == 0) {
        float a00=Amat[0],a01=Amat[1],a02=Amat[2];
        float a10=Amat[3],a11=Amat[4],a12=Amat[5];
        float a20=Amat[6],a21=Amat[7],a22=Amat[8];
        float c00 =  (a11*a22 - a12*a21);
        float c01 = -(a10*a22 - a12*a20);
        float c02 =  (a10*a21 - a11*a20);
        float det = a00*c00 + a01*c01 + a02*c02;
        float id  = 1.0f/det;
        invAS[0] =  c00*id;
        invAS[1] = -(a01*a22 - a02*a21)*id;
        invAS[2] =  (a01*a12 - a02*a11)*id;
        invAS[3] =  c01*id;
        invAS[4] =  (a00*a22 - a02*a20)*id;
        invAS[5] = -(a00*a12 - a02*a10)*id;
        invAS[6] =  c02*id;
        invAS[7] = -(a00*a21 - a01*a20)*id;
        invAS[8] =  (a00*a11 - a01*a10)*id;
        scaleS   = rsqrtf(fabsf(det));
    }
    __syncthreads();

    if (tid < NT) {
        int rg = r_base + tid;
        float r0 = rpts[rg*3+0], r1 = rpts[rg*3+1], r2 = rpts[rg*3+2];
        fracS[tid][0] = r0*invAS[0] + r1*invAS[3] + r2*invAS[6];
        fracS[tid][1] = r0*invAS[1] + r1*invAS[4] + r2*invAS[7];
        fracS[tid][2] = r0*invAS[2] + r1*invAS[5] + r2*invAS[8];
    }
    __syncthreads();

    f32x4 accRe[4][2], accIm[4][2];
    #pragma unroll
    for (int mi = 0; mi < 4; ++mi)
        #pragma unroll
        for (int ni = 0; ni < 2; ++ni) {
            accRe[mi][ni] = (f32x4){0.f,0.f,0.f,0.f};
            accIm[mi][ni] = (f32x4){0.f,0.f,0.f,0.f};
        }

    const int lane = tid & 63;
    const int wid  = tid >> 6;     // 0..3
    const int wm   = wid >> 1;     // 0..1 (M half: 64 rows)
    const int wn   = wid & 1;      // 0..1 (N half: 32 cols)
    const int frow = lane & 15;
    const int kq   = lane >> 4;

    const int sB   = tid >> 2;     // B stage row 0..63
    const int qtr  = tid & 3;      // k granule 0..3
    const int stOffB = swz(sB, qtr);
    const int aOff   = swz(wm*64 + frow, kq);
    const int bOff   = swz(wn*32 + frow, kq);

    const float f0r = fracS[sB][0], f1r = fracS[sB][1], f2r = fracS[sB][2];

    // recurrence constants: w1 = e^{2pi i f2}, w1wd = w1*e^{-2pi i 20 f2}
    float u1 = f2r - floorf(f2r);
    const float w1c = cos_rev(u1), w1s = sin_rev(u1);
    float yd = -20.0f * f2r; yd -= floorf(yd);
    const float wdc = cos_rev(yd), wds = sin_rev(yd);
    const float w1wdc = w1c*wdc - w1s*wds;
    const float w1wds = w1c*wds + w1s*wdc;

    #pragma unroll 1
    for (int t = 0; t < NTILES; ++t) {
        const int kb = k_begin + t*KK;

        // ---- stage A ----
        if (PRE) {
            // pre-swizzled bf16 tiles: 4x global_load_lds (linear dest)
            const char* tb = ws + (size_t)(kc*NTILES + t)*WS_TILE_B;
            glds16(tb +         tid*16,        smem + S_AR +        tid*16);
            glds16(tb + 4096 +  tid*16,        smem + S_AR + 4096 + tid*16);
            glds16(tb + 8192 +  tid*16,        smem + S_AI +        tid*16);
            glds16(tb + 12288 + tid*16,        smem + S_AI + 4096 + tid*16);
        } else {
            #pragma unroll
            for (int j = 0; j < 2; ++j) {
                int row = (tid>>2) + 64*j;
                int kg  = qtr ^ ((row>>1)&3);
                int k   = kb + kg*8;
                const float4 v0r = *(const float4*)&cgr[(size_t)row*NG + k];
                const float4 v1r = *(const float4*)&cgr[(size_t)row*NG + k + 4];
                const float4 v0i = *(const float4*)&cgi[(size_t)row*NG + k];
                const float4 v1i = *(const float4*)&cgi[(size_t)row*NG + k + 4];
                uint4 pr, pi;
                pr.x = cvt_pk(v0r.x, v0r.y); pr.y = cvt_pk(v0r.z, v0r.w);
                pr.z = cvt_pk(v1r.x, v1r.y); pr.w = cvt_pk(v1r.z, v1r.w);
                pi.x = cvt_pk(v0i.x, v0i.y); pi.y = cvt_pk(v0i.z, v0i.w);
                pi.z = cvt_pk(v1i.x, v1i.y); pi.w = cvt_pk(v1i.z, v1i.w);
                *(uint4*)(smem + S_AR + row*64 + qtr*16) = pr;
                *(uint4*)(smem + S_AI + row*64 + qtr*16) = pi;
            }
        }

        // ---- stage B: 8-phase run by complex recurrence ----
        {
            int g0   = kb + qtr*8;
            int i12  = (g0 * 3277) >> 16;            // g0/20 (exact, g0<16000)
            int i3_0 = g0 - i12*20;
            int i1a  = (i12 * 3277) >> 16; int i2a = i12 - i1a*20;
            int i12b = i12 + 1;
            int i1b  = (i12b * 3277) >> 16; int i2b = i12b - i1b*20;
            float m1a = (float)(i1a - (i1a >= 10 ? 20 : 0));
            float m2a = (float)(i2a - (i2a >= 10 ? 20 : 0));
            float m1b = (float)(i1b - (i1b >= 10 ? 20 : 0));
            float m2b = (float)(i2b - (i2b >= 10 ? 20 : 0));
            float m30 = (float)(i3_0 - (i3_0 >= 10 ? 20 : 0));
            float y0 = m1a*f0r + m2a*f1r + m30*f2r; y0 -= floorf(y0);
            float cc = cos_rev(y0), cs = sin_rev(y0);
            float rd = (m1b-m1a)*f0r + (m2b-m2a)*f1r; rd -= floorf(rd);
            float rc = cos_rev(rd), rs = sin_rev(rd);
            float wXc = w1c*rc - w1s*rs;
            float wXs = w1c*rs + w1s*rc;
            float bcv[8], bsv[8];
            bcv[0] = cc; bsv[0] = cs;
            #pragma unroll
            for (int j = 1; j < 8; ++j) {
                bool cB = (i3_0 == 20 - j);   // i12 boundary
                bool cD = (i3_0 == 10 - j);   // m3 decade jump
                float mc = cB ? wXc : (cD ? w1wdc : w1c);
                float ms = cB ? wXs : (cD ? w1wds : w1s);
                float nc = cc*mc - cs*ms;
                float ns = cc*ms + cs*mc;
                cc = nc; cs = ns;
                bcv[j] = cc; bsv[j] = cs;
            }
            uint4 wc, wsn;
            wc.x  = cvt_pk(bcv[0], bcv[1]); wc.y  = cvt_pk(bcv[2], bcv[3]);
            wc.z  = cvt_pk(bcv[4], bcv[5]); wc.w  = cvt_pk(bcv[6], bcv[7]);
            wsn.x = cvt_pk(bsv[0], bsv[1]); wsn.y = cvt_pk(bsv[2], bsv[3]);
            wsn.z = cvt_pk(bsv[4], bsv[5]); wsn.w = cvt_pk(bsv[6], bsv[7]);
            *(uint4*)(smem + S_BC + stOffB) = wc;
            *(uint4*)(smem + S_BS + stOffB) = wsn;
        }
        __syncthreads();   // RAW (also drains glds vmcnt)

        // ---- consume: wave tile 64m x 32n ----
        s16x8 bcf[2], bsf[2], bsnf[2];
        #pragma unroll
        for (int ni = 0; ni < 2; ++ni) {
            bcf[ni]  = *(const s16x8*)(smem + S_BC + bOff + ni*1024);
            bsf[ni]  = *(const s16x8*)(smem + S_BS + bOff + ni*1024);
            bsnf[ni] = bneg(bsf[ni]);
        }
        #pragma unroll
        for (int mi = 0; mi < 4; ++mi) {
            s16x8 arf = *(const s16x8*)(smem + S_AR + aOff + mi*1024);
            s16x8 aif = *(const s16x8*)(smem + S_AI + aOff + mi*1024);
            #pragma unroll
            for (int ni = 0; ni < 2; ++ni) {
                accRe[mi][ni] = __builtin_amdgcn_mfma_f32_16x16x32_bf16(arf, bcf[ni],  accRe[mi][ni], 0, 0, 0);
                accRe[mi][ni] = __builtin_amdgcn_mfma_f32_16x16x32_bf16(aif, bsnf[ni], accRe[mi][ni], 0, 0, 0);
                accIm[mi][ni] = __builtin_amdgcn_mfma_f32_16x16x32_bf16(arf, bsf[ni],  accIm[mi][ni], 0, 0, 0);
                accIm[mi][ni] = __builtin_amdgcn_mfma_f32_16x16x32_bf16(aif, bcf[ni],  accIm[mi][ni], 0, 0, 0);
            }
        }
        __syncthreads();   // WAR
    }

    // ---- e^{i k.r} table, overlaid on tile LDS; one sincos per thread ----
    float2* ekr = (float2*)smem;   // [64][4]
    {
        int col = tid >> 2, kidx = tid & 3;
        int rg = r_base + col;
        float r0 = rpts[rg*3+0], r1 = rpts[rg*3+1], r2 = rpts[rg*3+2];
        float ang = (r0*kgrid[kidx*3+0] + r1*kgrid[kidx*3+1] + r2*kgrid[kidx*3+2])
                    * 0.15915494309189535f;
        float u = ang - floorf(ang);
        ekr[col*4+kidx] = make_float2(cos_rev(u), sin_rev(u));
    }
    __syncthreads();

    // ---- epilogue: rotate by exp(i k.r), scale, atomic-accumulate ----
    const bool write_imag = (out_size >= 2*NSKIN*NRPT);
    const float scale = scaleS;
    #pragma unroll
    for (int mi = 0; mi < 4; ++mi) {
        const int m0 = wm*64 + mi*16;
        const int kidx = (m0 >> 4) & 3;
        #pragma unroll
        for (int ni = 0; ni < 2; ++ni) {
            int col = wn*32 + ni*16 + frow;
            int rg = r_base + col;
            float2 e = ekr[col*4+kidx];
            float ck = e.x, sk = e.y;
            #pragma unroll
            for (int v = 0; v < 4; ++v) {
                int sg = m0 + kq*4 + v;
                float re = accRe[mi][ni][v];
                float im = accIm[mi][ni][v];
                float orr = (re*ck - im*sk) * scale;
                size_t lin = (size_t)sg * NRPT + rg;
                if (write_imag) {
                    float oi = (re*sk + im*ck) * scale;
                    size_t idx = lin * 2;
                    if (idx + 1 < (size_t)out_size) {
                        atomicAdd(&out[idx],   orr);
                        atomicAdd(&out[idx+1], oi);
                    }
                } else {
                    atomicAdd(&out[lin], orr);
                }
            }
        }
    }
}

extern "C" void kernel_launch(void* const* d_in, const int* in_sizes, int n_in,
                              void* d_out, int out_size, void* d_ws, size_t ws_size,
                              hipStream_t stream) {
    const float* Amat  = (const float*)d_in[0];
    const float* kgrid = (const float*)d_in[1];
    const float* cgr   = (const float*)d_in[2];
    const float* cgi   = (const float*)d_in[3];
    const float* rpts  = (const float*)d_in[4];
    float* out = (float*)d_out;

    hipMemsetAsync(d_out, 0, (size_t)out_size * sizeof(float), stream);

    const bool use_pre = (ws_size >= WS_NEED);
    dim3 grid(NKC * 128);   // kc = bid>>7, rb = bid&127 (3 dead bids per kc)
    if (use_pre) {
        bloch_prepass<<<dim3(NKC*NTILES*2*512/256), 256, 0, stream>>>(cgr, cgi, (char*)d_ws);
        bloch7<true><<<grid, TPB, 0, stream>>>(Amat, kgrid, cgr, cgi, rpts,
                                               (const char*)d_ws, out, out_size);
    } else {
        bloch7<false><<<grid, TPB, 0, stream>>>(Amat, kgrid, cgr, cgi, rpts,
                                                nullptr, out, out_size);
    }
}

// Round 9
// 88.556 us; speedup vs baseline: 3.8379x; 3.8379x over previous
//
#include <hip/hip_runtime.h>

typedef __attribute__((ext_vector_type(4))) float f32x4;
typedef __attribute__((ext_vector_type(8))) short s16x8;

#define NG     8000
#define NRPT   8000
#define NSKIN  128
#define MT     128
#define NT     64
#define KK     32
#define KCH    800
#define NKC    10
#define NTILES 25          // KCH/KK exact
#define NRB    125         // NRPT/NT exact
#define TPB    256
#define WS_TILE_B 16384    // per K-tile: Ar 8KB + Ai 8KB, pre-swizzled bf16
#define WS_NEED   ((size_t)NKC*NTILES*WS_TILE_B)   // 4,096,000 B

// LDS byte offsets inside smem
#define S_AR 0
#define S_AI 8192
#define S_BC 16384
#define S_BS 20480
#define S_SZ 24576

__device__ __forceinline__ float sin_rev(float u){ float r; asm("v_sin_f32 %0, %1" : "=v"(r) : "v"(u)); return r; }
__device__ __forceinline__ float cos_rev(float u){ float r; asm("v_cos_f32 %0, %1" : "=v"(r) : "v"(u)); return r; }
__device__ __forceinline__ unsigned int cvt_pk(float lo, float hi){
    unsigned int r; asm("v_cvt_pk_bf16_f32 %0, %1, %2" : "=v"(r) : "v"(lo), "v"(hi)); return r;
}
__device__ __forceinline__ s16x8 bneg(s16x8 v){
    int4 u = *(int4*)&v;
    u.x ^= 0x80008000; u.y ^= 0x80008000; u.z ^= 0x80008000; u.w ^= 0x80008000;
    return *(s16x8*)&u;
}
// swizzled byte offset of 16B granule (row,kg) in a [rows][32]-ushort tile (64B rows).
// kg' = kg ^ ((row>>1)&3): both b128 stage-writes and b128 frag reads land
// 8 lanes per 16B bank-group -> conflict-free. Invariant under row+16 (+1024B).
__device__ __forceinline__ int swz(int row, int kg){
    return row*64 + ((kg ^ ((row>>1)&3))<<4);
}
__device__ __forceinline__ void glds16(const void* g, void* l){
    __builtin_amdgcn_global_load_lds((const __attribute__((address_space(1))) void*)g,
                                     (__attribute__((address_space(3))) void*)l, 16, 0, 0);
}

// ---- pre-pass: cg fp32 -> bf16 in pre-swizzled K-tile order ----
// ws granule gid (16B): gid = ((kc*25+t)*2 + plane)*512 + row*4 + slot
// content = bf16 of cg[row][kc*800 + t*32 + kg*8 .. +8], kg = slot ^ ((row>>1)&3)
__global__ __launch_bounds__(256) void bloch_prepass(
    const float* __restrict__ cgr, const float* __restrict__ cgi,
    char* __restrict__ ws)
{
    int gid = blockIdx.x*256 + threadIdx.x;
    if (gid >= NKC*NTILES*2*512) return;
    int slot  = gid & 3;
    int row   = (gid >> 2) & 127;
    int pt    = gid >> 9;
    int plane = pt & 1;
    int tileIdx = pt >> 1;          // kc*25 + t
    int t  = tileIdx % NTILES;
    int kc = tileIdx / NTILES;
    int kg = slot ^ ((row >> 1) & 3);
    int k  = kc*KCH + t*KK + kg*8;
    const float* src = plane ? cgi : cgr;
    const float4 v0 = *(const float4*)&src[(size_t)row*NG + k];
    const float4 v1 = *(const float4*)&src[(size_t)row*NG + k + 4];
    uint4 p;
    p.x = cvt_pk(v0.x, v0.y); p.y = cvt_pk(v0.z, v0.w);
    p.z = cvt_pk(v1.x, v1.y); p.w = cvt_pk(v1.z, v1.w);
    *(uint4*)(ws + (size_t)gid*16) = p;
}

// __launch_bounds__(256, 4): 4 waves/EU -> VGPR cap 128 (acc=64 + frags + temps
// fits; the R8 failure was (256,6) capping VGPR at ~85 -> acc spilled to scratch,
// 1.5 GB/dispatch scratch traffic). 4 blocks/CU, LDS 4x26KB=104KB.
template<bool PRE>
__global__ __launch_bounds__(TPB, 4) void bloch8(
    const float* __restrict__ Amat, const float* __restrict__ kgrid,
    const float* __restrict__ cgr,  const float* __restrict__ cgi,
    const float* __restrict__ rpts, const char* __restrict__ ws,
    float* __restrict__ out, int out_size)
{
    __shared__ __align__(16) char smem[S_SZ];   // A(16K)|Bc(4K)|Bs(4K); ekr overlay after loop
    __shared__ float fracS[NT][4];
    __shared__ float invAS[9];
    __shared__ float scaleS;

    const int tid = threadIdx.x;
    const int bid = blockIdx.x;
    // kc-partners of an output tile are 128 apart in bid -> same bid%8 -> same XCD
    const int kc  = bid >> 7;           // 0..9
    const int rb  = bid & 127;          // 0..127
    if (rb >= NRB) return;              // whole block returns (uniform) - no sync hazard
    const int r_base  = rb * NT;
    const int k_begin = kc * KCH;

    if (tid == 0) {
        float a00=Amat[0],a01=Amat[1],a02=Amat[2];
        float a10=Amat[3],a11=Amat[4],a12=Amat[5];
        float a20=Amat[6],a21=Amat[7],a22=Amat[8];
        float c00 =  (a11*a22 - a12*a21);
        float c01 = -(a10*a22 - a12*a20);
        float c02 =  (a10*a21 - a11*a20);
        float det = a00*c00 + a01*c01 + a02*c02;
        float id  = 1.0f/det;
        invAS[0] =  c00*id;
        invAS[1] = -(a01*a22 - a02*a21)*id;
        invAS[2] =  (a01*a12 - a02*a11)*id;
        invAS[3] =  c01*id;
        invAS[4] =  (a00*a22 - a02*a20)*id;
        invAS[5] = -(a00*a12 - a02*a10)*id;
        invAS[6] =  c02*id;
        invAS[7] = -(a00*a21 - a01*a20)*id;
        invAS[8] =  (a00*a11 - a01*a10)*id;
        scaleS   = rsqrtf(fabsf(det));
    }
    __syncthreads();

    if (tid < NT) {
        int rg = r_base + tid;
        float r0 = rpts[rg*3+0], r1 = rpts[rg*3+1], r2 = rpts[rg*3+2];
        fracS[tid][0] = r0*invAS[0] + r1*invAS[3] + r2*invAS[6];
        fracS[tid][1] = r0*invAS[1] + r1*invAS[4] + r2*invAS[7];
        fracS[tid][2] = r0*invAS[2] + r1*invAS[5] + r2*invAS[8];
    }
    __syncthreads();

    f32x4 accRe[4][2], accIm[4][2];
    #pragma unroll
    for (int mi = 0; mi < 4; ++mi)
        #pragma unroll
        for (int ni = 0; ni < 2; ++ni) {
            accRe[mi][ni] = (f32x4){0.f,0.f,0.f,0.f};
            accIm[mi][ni] = (f32x4){0.f,0.f,0.f,0.f};
        }

    const int lane = tid & 63;
    const int wid  = tid >> 6;     // 0..3
    const int wm   = wid >> 1;     // 0..1 (M half: 64 rows)
    const int wn   = wid & 1;      // 0..1 (N half: 32 cols)
    const int frow = lane & 15;
    const int kq   = lane >> 4;

    const int sB   = tid >> 2;     // B stage row 0..63
    const int qtr  = tid & 3;      // k granule 0..3
    const int stOffB = swz(sB, qtr);
    const int aOff   = swz(wm*64 + frow, kq);
    const int bOff   = swz(wn*32 + frow, kq);

    const float f0r = fracS[sB][0], f1r = fracS[sB][1], f2r = fracS[sB][2];

    // recurrence constants: w1 = e^{2pi i f2}, w1wd = w1*e^{-2pi i 20 f2}
    float u1 = f2r - floorf(f2r);
    const float w1c = cos_rev(u1), w1s = sin_rev(u1);
    float yd = -20.0f * f2r; yd -= floorf(yd);
    const float wdc = cos_rev(yd), wds = sin_rev(yd);
    const float w1wdc = w1c*wdc - w1s*wds;
    const float w1wds = w1c*wds + w1s*wdc;

    #pragma unroll 1
    for (int t = 0; t < NTILES; ++t) {
        const int kb = k_begin + t*KK;

        // ---- stage A ----
        if (PRE) {
            // pre-swizzled bf16 tiles: 4x global_load_lds (linear dest, zero VALU)
            const char* tb = ws + (size_t)(kc*NTILES + t)*WS_TILE_B;
            glds16(tb +         tid*16,        smem + S_AR +        tid*16);
            glds16(tb + 4096 +  tid*16,        smem + S_AR + 4096 + tid*16);
            glds16(tb + 8192 +  tid*16,        smem + S_AI +        tid*16);
            glds16(tb + 12288 + tid*16,        smem + S_AI + 4096 + tid*16);
        } else {
            #pragma unroll
            for (int j = 0; j < 2; ++j) {
                int row = (tid>>2) + 64*j;
                int kg  = qtr ^ ((row>>1)&3);
                int k   = kb + kg*8;
                const float4 v0r = *(const float4*)&cgr[(size_t)row*NG + k];
                const float4 v1r = *(const float4*)&cgr[(size_t)row*NG + k + 4];
                const float4 v0i = *(const float4*)&cgi[(size_t)row*NG + k];
                const float4 v1i = *(const float4*)&cgi[(size_t)row*NG + k + 4];
                uint4 pr, pi;
                pr.x = cvt_pk(v0r.x, v0r.y); pr.y = cvt_pk(v0r.z, v0r.w);
                pr.z = cvt_pk(v1r.x, v1r.y); pr.w = cvt_pk(v1r.z, v1r.w);
                pi.x = cvt_pk(v0i.x, v0i.y); pi.y = cvt_pk(v0i.z, v0i.w);
                pi.z = cvt_pk(v1i.x, v1i.y); pi.w = cvt_pk(v1i.z, v1i.w);
                *(uint4*)(smem + S_AR + row*64 + qtr*16) = pr;
                *(uint4*)(smem + S_AI + row*64 + qtr*16) = pi;
            }
        }

        // ---- stage B: 8-phase run by complex recurrence ----
        {
            int g0   = kb + qtr*8;
            int i12  = (g0 * 3277) >> 16;            // g0/20 (exact, g0<16000)
            int i3_0 = g0 - i12*20;
            int i1a  = (i12 * 3277) >> 16; int i2a = i12 - i1a*20;
            int i12b = i12 + 1;
            int i1b  = (i12b * 3277) >> 16; int i2b = i12b - i1b*20;
            float m1a = (float)(i1a - (i1a >= 10 ? 20 : 0));
            float m2a = (float)(i2a - (i2a >= 10 ? 20 : 0));
            float m1b = (float)(i1b - (i1b >= 10 ? 20 : 0));
            float m2b = (float)(i2b - (i2b >= 10 ? 20 : 0));
            float m30 = (float)(i3_0 - (i3_0 >= 10 ? 20 : 0));
            float y0 = m1a*f0r + m2a*f1r + m30*f2r; y0 -= floorf(y0);
            float cc = cos_rev(y0), cs = sin_rev(y0);
            float rd = (m1b-m1a)*f0r + (m2b-m2a)*f1r; rd -= floorf(rd);
            float rc = cos_rev(rd), rs = sin_rev(rd);
            float wXc = w1c*rc - w1s*rs;
            float wXs = w1c*rs + w1s*rc;
            float bcv[8], bsv[8];
            bcv[0] = cc; bsv[0] = cs;
            #pragma unroll
            for (int j = 1; j < 8; ++j) {
                bool cB = (i3_0 == 20 - j);   // i12 boundary
                bool cD = (i3_0 == 10 - j);   // m3 decade jump
                float mc = cB ? wXc : (cD ? w1wdc : w1c);
                float ms = cB ? wXs : (cD ? w1wds : w1s);
                float nc = cc*mc - cs*ms;
                float ns = cc*ms + cs*mc;
                cc = nc; cs = ns;
                bcv[j] = cc; bsv[j] = cs;
            }
            uint4 wc, wsn;
            wc.x  = cvt_pk(bcv[0], bcv[1]); wc.y  = cvt_pk(bcv[2], bcv[3]);
            wc.z  = cvt_pk(bcv[4], bcv[5]); wc.w  = cvt_pk(bcv[6], bcv[7]);
            wsn.x = cvt_pk(bsv[0], bsv[1]); wsn.y = cvt_pk(bsv[2], bsv[3]);
            wsn.z = cvt_pk(bsv[4], bsv[5]); wsn.w = cvt_pk(bsv[6], bsv[7]);
            *(uint4*)(smem + S_BC + stOffB) = wc;
            *(uint4*)(smem + S_BS + stOffB) = wsn;
        }
        __syncthreads();   // RAW (also drains glds vmcnt)

        // ---- consume: wave tile 64m x 32n ----
        s16x8 bcf[2], bsf[2], bsnf[2];
        #pragma unroll
        for (int ni = 0; ni < 2; ++ni) {
            bcf[ni]  = *(const s16x8*)(smem + S_BC + bOff + ni*1024);
            bsf[ni]  = *(const s16x8*)(smem + S_BS + bOff + ni*1024);
            bsnf[ni] = bneg(bsf[ni]);
        }
        #pragma unroll
        for (int mi = 0; mi < 4; ++mi) {
            s16x8 arf = *(const s16x8*)(smem + S_AR + aOff + mi*1024);
            s16x8 aif = *(const s16x8*)(smem + S_AI + aOff + mi*1024);
            #pragma unroll
            for (int ni = 0; ni < 2; ++ni) {
                accRe[mi][ni] = __builtin_amdgcn_mfma_f32_16x16x32_bf16(arf, bcf[ni],  accRe[mi][ni], 0, 0, 0);
                accRe[mi][ni] = __builtin_amdgcn_mfma_f32_16x16x32_bf16(aif, bsnf[ni], accRe[mi][ni], 0, 0, 0);
                accIm[mi][ni] = __builtin_amdgcn_mfma_f32_16x16x32_bf16(arf, bsf[ni],  accIm[mi][ni], 0, 0, 0);
                accIm[mi][ni] = __builtin_amdgcn_mfma_f32_16x16x32_bf16(aif, bcf[ni],  accIm[mi][ni], 0, 0, 0);
            }
        }
        __syncthreads();   // WAR
    }

    // ---- e^{i k.r} table, overlaid on tile LDS; one sincos per thread ----
    float2* ekr = (float2*)smem;   // [64][4]
    {
        int col = tid >> 2, kidx = tid & 3;
        int rg = r_base + col;
        float r0 = rpts[rg*3+0], r1 = rpts[rg*3+1], r2 = rpts[rg*3+2];
        float ang = (r0*kgrid[kidx*3+0] + r1*kgrid[kidx*3+1] + r2*kgrid[kidx*3+2])
                    * 0.15915494309189535f;
        float u = ang - floorf(ang);
        ekr[col*4+kidx] = make_float2(cos_rev(u), sin_rev(u));
    }
    __syncthreads();

    // ---- epilogue: rotate by exp(i k.r), scale, atomic-accumulate ----
    const bool write_imag = (out_size >= 2*NSKIN*NRPT);
    const float scale = scaleS;
    #pragma unroll
    for (int mi = 0; mi < 4; ++mi) {
        const int m0 = wm*64 + mi*16;
        const int kidx = (m0 >> 4) & 3;
        #pragma unroll
        for (int ni = 0; ni < 2; ++ni) {
            int col = wn*32 + ni*16 + frow;
            int rg = r_base + col;
            float2 e = ekr[col*4+kidx];
            float ck = e.x, sk = e.y;
            #pragma unroll
            for (int v = 0; v < 4; ++v) {
                int sg = m0 + kq*4 + v;
                float re = accRe[mi][ni][v];
                float im = accIm[mi][ni][v];
                float orr = (re*ck - im*sk) * scale;
                size_t lin = (size_t)sg * NRPT + rg;
                if (write_imag) {
                    float oi = (re*sk + im*ck) * scale;
                    size_t idx = lin * 2;
                    if (idx + 1 < (size_t)out_size) {
                        atomicAdd(&out[idx],   orr);
                        atomicAdd(&out[idx+1], oi);
                    }
                } else {
                    atomicAdd(&out[lin], orr);
                }
            }
        }
    }
}

extern "C" void kernel_launch(void* const* d_in, const int* in_sizes, int n_in,
                              void* d_out, int out_size, void* d_ws, size_t ws_size,
                              hipStream_t stream) {
    const float* Amat  = (const float*)d_in[0];
    const float* kgrid = (const float*)d_in[1];
    const float* cgr   = (const float*)d_in[2];
    const float* cgi   = (const float*)d_in[3];
    const float* rpts  = (const float*)d_in[4];
    float* out = (float*)d_out;

    hipMemsetAsync(d_out, 0, (size_t)out_size * sizeof(float), stream);

    const bool use_pre = (ws_size >= WS_NEED);
    dim3 grid(NKC * 128);   // kc = bid>>7, rb = bid&127 (3 dead bids per kc)
    if (use_pre) {
        bloch_prepass<<<dim3(NKC*NTILES*2*512/256), 256, 0, stream>>>(cgr, cgi, (char*)d_ws);
        bloch8<true><<<grid, TPB, 0, stream>>>(Amat, kgrid, cgr, cgi, rpts,
                                               (const char*)d_ws, out, out_size);
    } else {
        bloch8<false><<<grid, TPB, 0, stream>>>(Amat, kgrid, cgr, cgi, rpts,
                                                nullptr, out, out_size);
    }
}